// Round 8
// baseline (581.466 us; speedup 1.0000x reference)
//
#include <hip/hip_runtime.h>

#define N_NODES 100000
#define N_EDGES 1600000
#define IN_DIM 160
#define HID 128
#define BN_EPS 1e-5f

#define M_PAD 100096   // 1564 * 64 rows (GEMM block = 64 rows)
#define NBUCK 196      // 512-node buckets (196*512 = 100352 >= N_NODES)
#define BSH 9
#define EPB 8192       // edges per block in hist/scatter kernels
#define NHB (NBUCK * NBUCK)   // 38416, divisible by 4
#define NSB 38         // scan blocks: 38*1024 = 38912 >= NHB
#define LPAD 132       // gemm LDS repack row stride (ushorts)

typedef unsigned int uint;
typedef unsigned short ushort;
typedef __attribute__((ext_vector_type(8))) short bf16x8;
typedef __attribute__((ext_vector_type(4))) float f32x4;
typedef __attribute__((ext_vector_type(2))) float f32x2;

__device__ __forceinline__ ushort bf16rn(float f) {
    uint u = __float_as_uint(f);
    u += 0x7fffu + ((u >> 16) & 1u);
    return (ushort)(u >> 16);
}
__device__ __forceinline__ float bflo(uint u) { return __uint_as_float(u << 16); }
__device__ __forceinline__ float bfhi(uint u) { return __uint_as_float(u & 0xffff0000u); }

// ---------------------------------------------------------------------------
// CSR build via two-level bucket sort -> PADDED per-node edge lists.
// Padding entries point at row N_NODES (guaranteed all-zero in tl) so the
// aggregation needs no per-edge masking.
// ---------------------------------------------------------------------------

__global__ __launch_bounds__(256) void hist_kernel(const int* __restrict__ dst,
                                                   int* __restrict__ ghist) {
    __shared__ int hist[NBUCK];
    int b = blockIdx.x, t = threadIdx.x;
    for (int i = t; i < NBUCK; i += 256) hist[i] = 0;
    __syncthreads();
    int e0 = b * EPB;
    for (int i = 0; i < EPB; i += 256) {
        int e = e0 + i + t;
        if (e < N_EDGES) atomicAdd(&hist[dst[e] >> BSH], 1);
    }
    __syncthreads();
    for (int i = t; i < NBUCK; i += 256) ghist[i * NBUCK + b] = hist[i];
}

__global__ __launch_bounds__(256) void scan1_kernel(const int* __restrict__ ghist,
                                                    int* __restrict__ bsum) {
    __shared__ int wsum[4];
    int b = blockIdx.x, t = threadIdx.x;
    int i4 = b * 256 + t;
    int4 v = (i4 * 4 < NHB) ? ((const int4*)ghist)[i4] : make_int4(0, 0, 0, 0);
    int s = v.x + v.y + v.z + v.w;
#pragma unroll
    for (int off = 32; off; off >>= 1) s += __shfl_down(s, off);
    if ((t & 63) == 0) wsum[t >> 6] = s;
    __syncthreads();
    if (t == 0) bsum[b] = wsum[0] + wsum[1] + wsum[2] + wsum[3];
}

__global__ void scan2_kernel(const int* __restrict__ bsum, int* __restrict__ boff,
                             int* __restrict__ gbb) {
    int lane = threadIdx.x;
    int v = (lane < NSB) ? bsum[lane] : 0;
    int s = v;
#pragma unroll
    for (int off = 1; off <= 32; off <<= 1) {
        int t2 = __shfl_up(s, off);
        if (lane >= off) s += t2;
    }
    if (lane < NSB) boff[lane] = s - v;
    if (lane == 0) gbb[NBUCK] = N_EDGES;
}

__global__ __launch_bounds__(256) void scan3_kernel(int* __restrict__ ghist,
                                                    const int* __restrict__ boff,
                                                    int* __restrict__ gbb) {
    __shared__ int ts[256];
    int b = blockIdx.x, t = threadIdx.x;
    int i4 = b * 256 + t;
    bool ok = (i4 * 4) < NHB;
    int4 v = ok ? ((const int4*)ghist)[i4] : make_int4(0, 0, 0, 0);
    int s = v.x + v.y + v.z + v.w;
    ts[t] = s;
    __syncthreads();
    for (int off = 1; off < 256; off <<= 1) {
        int a = (t >= off) ? ts[t - off] : 0;
        __syncthreads();
        ts[t] += a;
        __syncthreads();
    }
    int excl = boff[b] + ((t > 0) ? ts[t - 1] : 0);
    if (ok) {
        int idx = i4 * 4;
        int4 w;
        w.x = excl;
        w.y = excl + v.x;
        w.z = excl + v.x + v.y;
        w.w = excl + v.x + v.y + v.z;
        ((int4*)ghist)[i4] = w;
        if (idx % NBUCK == 0) gbb[idx / NBUCK] = w.x;
    }
}

__global__ __launch_bounds__(256) void scatter_kernel(const int* __restrict__ src,
                                                      const int* __restrict__ dst,
                                                      const int* __restrict__ ghist,
                                                      uint* __restrict__ scat) {
    __shared__ int base[NBUCK];
    __shared__ int fill[NBUCK];
    int b = blockIdx.x, t = threadIdx.x;
    for (int i = t; i < NBUCK; i += 256) { base[i] = ghist[i * NBUCK + b]; fill[i] = 0; }
    __syncthreads();
    int e0 = b * EPB;
    for (int i = 0; i < EPB; i += 256) {
        int e = e0 + i + t;
        if (e < N_EDGES) {
            int d = dst[e];
            int sv = src[e];
            int bk = d >> BSH;
            int lp = atomicAdd(&fill[bk], 1);
            scat[base[bk] + lp] = (uint)sv | ((uint)(d & 511) << 17);
        }
    }
}

__global__ __launch_bounds__(256) void bucket_csr_kernel(const uint* __restrict__ scat,
                                                         const int* __restrict__ gbb,
                                                         int* __restrict__ prow,
                                                         int* __restrict__ deg,
                                                         int* __restrict__ peidx) {
    __shared__ int cnt[512], fl[512], pref[512];
    __shared__ int ts[256];
    __shared__ int tot_s;
    int b = blockIdx.x, t = threadIdx.x;
    int beg = gbb[b], end = gbb[b + 1];
    int pb = beg + b * 8192;
    cnt[t] = 0; cnt[t + 256] = 0;
    __syncthreads();
    for (int i = beg + t; i < end; i += 256)
        atomicAdd(&cnt[scat[i] >> 17], 1);
    __syncthreads();
    int c0 = cnt[2 * t], c1 = cnt[2 * t + 1];
    int p0 = (c0 + 15) & ~15, p1 = (c1 + 15) & ~15;
    ts[t] = p0 + p1;
    __syncthreads();
    for (int off = 1; off < 256; off <<= 1) {
        int v = (t >= off) ? ts[t - off] : 0;
        __syncthreads();
        ts[t] += v;
        __syncthreads();
    }
    int ex = (t > 0) ? ts[t - 1] : 0;
    pref[2 * t] = ex;
    pref[2 * t + 1] = ex + p0;
    fl[t] = 0; fl[t + 256] = 0;
    if (t == 255) tot_s = ts[255];
    int g0 = b * 512 + 2 * t;
    if (g0 < N_NODES) { prow[g0] = pb + ex; deg[g0] = c0; }
    if (g0 + 1 < N_NODES) { prow[g0 + 1] = pb + ex + p0; deg[g0 + 1] = c1; }
    __syncthreads();
    int tot = tot_s;
    for (int i = t; i < tot; i += 256) peidx[pb + i] = N_NODES;  // pad -> zero row
    __syncthreads();
    for (int i = beg + t; i < end; i += 256) {
        uint w = scat[i];
        int nl = (int)(w >> 17);
        int lp = atomicAdd(&fl[nl], 1);
        peidx[pb + pref[nl] + lp] = (int)(w & 0x1FFFFu);
    }
}

// ---------------------------------------------------------------------------
// Prep
// ---------------------------------------------------------------------------
__global__ void prep_weights_kernel(const float* __restrict__ wl, const float* __restrict__ wr,
                                    ushort* __restrict__ Bt, int K) {
    int n = blockIdx.y;
    int k = blockIdx.x * 64 + threadIdx.x;
    if (k < K) {
        float v = (n < HID) ? wl[k * HID + n] : wr[k * HID + (n - HID)];
        Bt[n * K + k] = bf16rn(v);
    }
}

__global__ void bn_prep_kernel(const float* __restrict__ bl0, const float* __restrict__ g0,
                               const float* __restrict__ be0, const float* __restrict__ rm0,
                               const float* __restrict__ rv0,
                               const float* __restrict__ bl1, const float* __restrict__ g1,
                               const float* __restrict__ be1, const float* __restrict__ rm1,
                               const float* __restrict__ rv1,
                               const float* __restrict__ bl2, const float* __restrict__ g2,
                               const float* __restrict__ be2, const float* __restrict__ rm2,
                               const float* __restrict__ rv2,
                               float* __restrict__ scale, float* __restrict__ shift) {
    int t = threadIdx.x;
    int L = t >> 7, j = t & 127;
    const float* bl = (L == 0) ? bl0 : (L == 1) ? bl1 : bl2;
    const float* g  = (L == 0) ? g0  : (L == 1) ? g1  : g2;
    const float* be = (L == 0) ? be0 : (L == 1) ? be1 : be2;
    const float* rm = (L == 0) ? rm0 : (L == 1) ? rm1 : rm2;
    const float* rv = (L == 0) ? rv0 : (L == 1) ? rv1 : rv2;
    float s = g[j] * rsqrtf(rv[j] + BN_EPS);
    scale[t] = s;
    shift[t] = (bl[j] - rm[j]) * s + be[j];
}

// ---------------------------------------------------------------------------
// GEMM (merged N): [tl | troot] = A @ [wl | wr]. Block = 64 rows x 256 cols,
// grid 1564. A-tile staged once in LDS (XOR chunk swizzle); wave = 16 rows x
// 256 cols = 16 MFMA tiles. Epilogue repacks via per-wave LDS slice (aliases
// A-stage after a barrier) -> coalesced 256B row stores, two passes
// (cols 0..127 -> tl, 128..255 -> troot).
// ---------------------------------------------------------------------------
template <int K, bool AFP32>
__global__ __launch_bounds__(256) void gemm_kernel(const void* __restrict__ A_,
                                                   const ushort* __restrict__ Bt,
                                                   ushort* __restrict__ tl,
                                                   ushort* __restrict__ troot) {
    constexpr int CPR = (K * 2) / 16;          // 16B chunks per row
    constexpr int FULLG = CPR & ~7;            // start of partial swizzle group
    constexpr int LDSE = (64 * K > 4 * 16 * LPAD) ? 64 * K : 4 * 16 * LPAD;
    __shared__ ushort ldsA[LDSE];
    const int t = threadIdx.x;
    const int m0b = blockIdx.x * 64;

    // ---- Stage A tile (64 rows x K) ----
#pragma unroll
    for (int i = 0; i < (64 * CPR) / 256; ++i) {
        int cidx = i * 256 + t;
        int row = cidx / CPR;
        int j = cidx - row * CPR;
        bf16x8 v;
        if (AFP32) {
            const float* A = (const float*)A_;
            int m = m0b + row;
            float4 f0 = make_float4(0.f, 0.f, 0.f, 0.f), f1 = f0;
            if (m < N_NODES) {
                f0 = *(const float4*)(A + (size_t)m * K + j * 8);
                f1 = *(const float4*)(A + (size_t)m * K + j * 8 + 4);
            }
            v[0] = (short)bf16rn(f0.x); v[1] = (short)bf16rn(f0.y);
            v[2] = (short)bf16rn(f0.z); v[3] = (short)bf16rn(f0.w);
            v[4] = (short)bf16rn(f1.x); v[5] = (short)bf16rn(f1.y);
            v[6] = (short)bf16rn(f1.z); v[7] = (short)bf16rn(f1.w);
        } else {
            const ushort* A = (const ushort*)A_;
            v = *(const bf16x8*)(A + (size_t)(m0b + row) * K + j * 8);
        }
        int swz = (j < FULLG) ? ((j & ~7) | ((j ^ row) & 7))
                              : ((j & ~3) | ((j ^ row) & 3));
        *(bf16x8*)&ldsA[row * K + swz * 8] = v;
    }
    __syncthreads();

    // ---- K-loop: 16 MFMA tiles (256 cols) per wave ----
    const int lane = threadIdx.x & 63;
    const int wv = threadIdx.x >> 6;
    const int col = lane & 15;
    const int q = lane >> 4;
    const int row0 = wv * 16 + col;
    f32x4 acc[16];
#pragma unroll
    for (int tt = 0; tt < 16; ++tt) acc[tt] = (f32x4){0.f, 0.f, 0.f, 0.f};

#pragma unroll
    for (int k0 = 0; k0 < K; k0 += 32) {
        int jj = (k0 >> 3) + q;
        int swzj = (jj < FULLG) ? ((jj & ~7) | ((jj ^ col) & 7))
                                : ((jj & ~3) | ((jj ^ col) & 3));
        bf16x8 a0 = *(const bf16x8*)&ldsA[row0 * K + swzj * 8];
        int kk = k0 + q * 8;
#pragma unroll
        for (int tt = 0; tt < 16; ++tt) {
            bf16x8 bfr = *(const bf16x8*)(Bt + (size_t)(tt * 16 + col) * K + kk);
            acc[tt] = __builtin_amdgcn_mfma_f32_16x16x32_bf16(a0, bfr, acc[tt], 0, 0, 0);
        }
    }

    // ---- Epilogue: per-wave LDS repack, coalesced stores, 2 passes ----
    __syncthreads();   // all waves done reading A region before aliasing
    ushort(*rp)[16][LPAD] = (ushort(*)[16][LPAD])ldsA;
#pragma unroll
    for (int pass = 0; pass < 2; ++pass) {
        ushort* outp = pass ? troot : tl;
#pragma unroll
        for (int tt = 0; tt < 8; ++tt)
#pragma unroll
            for (int r = 0; r < 4; ++r)
                rp[wv][q * 4 + r][tt * 16 + col] = bf16rn(acc[pass * 8 + tt][r]);
        int mbase = m0b + wv * 16;
#pragma unroll
        for (int i = 0; i < 4; ++i) {
            int lin = i * 64 + lane;
            int row = lin >> 4;      // 4 rows per instr (16 lanes x 16B)
            int c16 = lin & 15;
            bf16x8 v = *(const bf16x8*)&rp[wv][row][c16 * 8];
            *(bf16x8*)(outp + (size_t)(mbase + row) * HID + c16 * 8) = v;
        }
    }
}

// ---------------------------------------------------------------------------
// Aggregation + BN + ReLU (+ fused final linear).
// Wave = 4 nodes (16 lanes each); per-lane addresses -> 4 edge rows (1024B)
// per vmem instruction. No per-edge masking: padding gathers hit the zero row
// (N_NODES). Grid covers M_PAD so h's pad rows are zeroed for the next GEMM.
// ---------------------------------------------------------------------------
template <bool FINAL>
__global__ __launch_bounds__(256) void agg_kernel(
    const ushort* __restrict__ tl_, const ushort* __restrict__ troot_,
    const int* __restrict__ prow, const int* __restrict__ deg_,
    const int* __restrict__ peidx,
    const float* __restrict__ bnscale, const float* __restrict__ bnshift,
    const float* __restrict__ linw, const float* __restrict__ linb,
    ushort* __restrict__ hout, float* __restrict__ out) {
    const int lane = threadIdx.x & 63;
    const int wvg = (blockIdx.x * 256 + (int)threadIdx.x) >> 6;
    const int g = lane >> 4;          // group 0..3 -> node
    const int s = lane & 15;          // feat slice: feats s*8 .. s*8+7
    const int n = wvg * 4 + g;        // < M_PAD by grid construction
    const int nn = (n < N_NODES) ? n : (N_NODES - 1);

    float4 sc0 = *(const float4*)(bnscale + s * 8);
    float4 sc1 = *(const float4*)(bnscale + s * 8 + 4);
    float4 sh0 = *(const float4*)(bnshift + s * 8);
    float4 sh1 = *(const float4*)(bnshift + s * 8 + 4);

    int pbeg = prow[nn];
    int dg = (n < N_NODES) ? deg_[nn] : 0;
    int myb = (dg + 15) >> 4;         // batches of 16 edges

    f32x2 acc2[4];
#pragma unroll
    for (int i = 0; i < 4; ++i) acc2[i] = (f32x2){0.f, 0.f};

    const int gsel = (lane & 48) << 2;   // bpermute byte-addr base of my group

    for (int b = 0;; ++b) {
        bool act = b < myb;
        if (!__any(act)) break;
        int idx = act ? peidx[pbeg + b * 16 + s] : N_NODES;  // 16 ids (or zero row)
        uint4 u[16];
#pragma unroll
        for (int jj = 0; jj < 16; ++jj) {
            int src = __builtin_amdgcn_ds_bpermute(gsel | (jj << 2), idx);
            u[jj] = *(const uint4*)(tl_ + (size_t)src * HID + s * 8);
        }
#pragma unroll
        for (int jj = 0; jj < 16; ++jj) {
            acc2[0] += (f32x2){bflo(u[jj].x), bfhi(u[jj].x)};
            acc2[1] += (f32x2){bflo(u[jj].y), bfhi(u[jj].y)};
            acc2[2] += (f32x2){bflo(u[jj].z), bfhi(u[jj].z)};
            acc2[3] += (f32x2){bflo(u[jj].w), bfhi(u[jj].w)};
        }
    }

    float inv = 1.0f / (float)((dg > 0) ? dg : 1);
    uint4 rv = *(const uint4*)(troot_ + (size_t)nn * HID + s * 8);
    float o[8];
    o[0] = fmaxf(fmaf(fmaf(acc2[0].x, inv, bflo(rv.x)), sc0.x, sh0.x), 0.f);
    o[1] = fmaxf(fmaf(fmaf(acc2[0].y, inv, bfhi(rv.x)), sc0.y, sh0.y), 0.f);
    o[2] = fmaxf(fmaf(fmaf(acc2[1].x, inv, bflo(rv.y)), sc0.z, sh0.z), 0.f);
    o[3] = fmaxf(fmaf(fmaf(acc2[1].y, inv, bfhi(rv.y)), sc0.w, sh0.w), 0.f);
    o[4] = fmaxf(fmaf(fmaf(acc2[2].x, inv, bflo(rv.z)), sc1.x, sh1.x), 0.f);
    o[5] = fmaxf(fmaf(fmaf(acc2[2].y, inv, bfhi(rv.z)), sc1.y, sh1.y), 0.f);
    o[6] = fmaxf(fmaf(fmaf(acc2[3].x, inv, bflo(rv.w)), sc1.z, sh1.z), 0.f);
    o[7] = fmaxf(fmaf(fmaf(acc2[3].y, inv, bfhi(rv.w)), sc1.w, sh1.w), 0.f);

    if (FINAL) {
        float4 w0 = *(const float4*)(linw + s * 8);
        float4 w1 = *(const float4*)(linw + s * 8 + 4);
        float p = o[0] * w0.x + o[1] * w0.y + o[2] * w0.z + o[3] * w0.w +
                  o[4] * w1.x + o[5] * w1.y + o[6] * w1.z + o[7] * w1.w;
#pragma unroll
        for (int off = 1; off < 16; off <<= 1) p += __shfl_xor(p, off);
        if (s == 0 && n < N_NODES) out[n] = p + linb[0];
    } else {
        uint4 pk = make_uint4(0u, 0u, 0u, 0u);
        if (n < N_NODES) {
            pk.x = (uint)bf16rn(o[0]) | ((uint)bf16rn(o[1]) << 16);
            pk.y = (uint)bf16rn(o[2]) | ((uint)bf16rn(o[3]) << 16);
            pk.z = (uint)bf16rn(o[4]) | ((uint)bf16rn(o[5]) << 16);
            pk.w = (uint)bf16rn(o[6]) | ((uint)bf16rn(o[7]) << 16);
        }
        *(uint4*)(hout + (size_t)n * HID + s * 8) = pk;   // pad rows -> zeros
    }
}

// ---------------------------------------------------------------------------

extern "C" void kernel_launch(void* const* d_in, const int* in_sizes, int n_in,
                              void* d_out, int out_size, void* d_ws, size_t ws_size,
                              hipStream_t stream) {
    const float* x    = (const float*)d_in[0];
    const int*   ei   = (const int*)d_in[1];
    const int*   esrc = ei;
    const int*   edst = ei + N_EDGES;
    const float* wl[3]; const float* wr[3]; const float* bl[3];
    const float* g[3];  const float* be[3]; const float* rm[3]; const float* rv[3];
    for (int i = 0; i < 3; ++i) {
        wl[i] = (const float*)d_in[2 + 7 * i];
        wr[i] = (const float*)d_in[3 + 7 * i];
        bl[i] = (const float*)d_in[4 + 7 * i];
        g[i]  = (const float*)d_in[5 + 7 * i];
        be[i] = (const float*)d_in[6 + 7 * i];
        rm[i] = (const float*)d_in[7 + 7 * i];
        rv[i] = (const float*)d_in[8 + 7 * i];
    }
    const float* lin_w = (const float*)d_in[23];
    const float* lin_b = (const float*)d_in[24];
    float* out = (float*)d_out;

    // Workspace carve-up (~98 MB total).
    char* ws = (char*)d_ws;
    size_t off = 0;
    auto carve = [&](size_t bytes) -> void* {
        void* p = ws + off;
        off += (bytes + 255) & ~(size_t)255;
        return p;
    };
    int*    prow   = (int*)carve((size_t)(N_NODES + 8) * sizeof(int));
    int*    deg    = (int*)carve((size_t)(N_NODES + 8) * sizeof(int));
    int*    peidx  = (int*)carve((size_t)3210000 * sizeof(int));   // padded CSR
    uint*   scat   = (uint*)carve((size_t)N_EDGES * sizeof(uint));
    int*    ghist  = (int*)carve((size_t)(NSB * 1024) * sizeof(int));
    int*    gbb    = (int*)carve((NBUCK + 4) * sizeof(int));
    int*    bsum   = (int*)carve((NSB + 2) * sizeof(int));
    int*    boff   = (int*)carve((NSB + 2) * sizeof(int));
    ushort* tl     = (ushort*)carve((size_t)(M_PAD + 1) * HID * sizeof(ushort));
    ushort* troot  = (ushort*)carve((size_t)M_PAD * HID * sizeof(ushort));
    ushort* h      = (ushort*)carve((size_t)M_PAD * HID * sizeof(ushort));
    ushort* Bt0    = (ushort*)carve(256 * IN_DIM * sizeof(ushort));
    ushort* Bt1    = (ushort*)carve(256 * HID * sizeof(ushort));
    ushort* Bt2    = (ushort*)carve(256 * HID * sizeof(ushort));
    float*  bnsc   = (float*)carve(3 * HID * sizeof(float));
    float*  bnsh   = (float*)carve(3 * HID * sizeof(float));
    (void)ws_size; (void)n_in; (void)in_sizes; (void)out_size;

    hist_kernel<<<NBUCK, 256, 0, stream>>>(edst, ghist);
    scan1_kernel<<<NSB, 256, 0, stream>>>(ghist, bsum);
    scan2_kernel<<<1, 64, 0, stream>>>(bsum, boff, gbb);
    scan3_kernel<<<NSB, 256, 0, stream>>>(ghist, boff, gbb);
    scatter_kernel<<<NBUCK, 256, 0, stream>>>(esrc, edst, ghist, scat);
    bucket_csr_kernel<<<NBUCK, 256, 0, stream>>>(scat, gbb, prow, deg, peidx);

    prep_weights_kernel<<<dim3((IN_DIM + 63) / 64, 256), 64, 0, stream>>>(wl[0], wr[0], Bt0, IN_DIM);
    prep_weights_kernel<<<dim3((HID + 63) / 64, 256), 64, 0, stream>>>(wl[1], wr[1], Bt1, HID);
    prep_weights_kernel<<<dim3((HID + 63) / 64, 256), 64, 0, stream>>>(wl[2], wr[2], Bt2, HID);
    bn_prep_kernel<<<1, 384, 0, stream>>>(bl[0], g[0], be[0], rm[0], rv[0],
                                          bl[1], g[1], be[1], rm[1], rv[1],
                                          bl[2], g[2], be[2], rm[2], rv[2],
                                          bnsc, bnsh);

    const int GEMM_GRID = M_PAD / 64;           // 1564 blocks, 256 cols each
    const int AGG_GRID = M_PAD / 16;            // 6256: covers pad rows too

    gemm_kernel<IN_DIM, true><<<GEMM_GRID, 256, 0, stream>>>(x, Bt0, tl, troot);
    agg_kernel<false><<<AGG_GRID, 256, 0, stream>>>(tl, troot, prow, deg, peidx, bnsc, bnsh,
                                                    nullptr, nullptr, h, nullptr);
    gemm_kernel<HID, false><<<GEMM_GRID, 256, 0, stream>>>(h, Bt1, tl, troot);
    agg_kernel<false><<<AGG_GRID, 256, 0, stream>>>(tl, troot, prow, deg, peidx, bnsc + HID, bnsh + HID,
                                                    nullptr, nullptr, h, nullptr);
    gemm_kernel<HID, false><<<GEMM_GRID, 256, 0, stream>>>(h, Bt2, tl, troot);
    agg_kernel<true><<<AGG_GRID, 256, 0, stream>>>(tl, troot, prow, deg, peidx, bnsc + 2 * HID, bnsh + 2 * HID,
                                                   lin_w, lin_b, nullptr, out);
}

// Round 9
// 536.290 us; speedup vs baseline: 1.0842x; 1.0842x over previous
//
#include <hip/hip_runtime.h>

#define N_NODES 100000
#define N_EDGES 1600000
#define IN_DIM 160
#define HID 128
#define BN_EPS 1e-5f

#define M_PAD 100096   // 782 * 128 rows (GEMM block = 128 rows)
#define NBUCK 196      // 512-node buckets (196*512 = 100352 >= N_NODES)
#define BSH 9
#define EPB 8192       // edges per block in hist/scatter kernels
#define NHB (NBUCK * NBUCK)   // 38416, divisible by 4
#define NSB 38         // scan blocks: 38*1024 = 38912 >= NHB
#define LPAD 132       // gemm LDS repack row stride (ushorts)

typedef unsigned int uint;
typedef unsigned short ushort;
typedef __attribute__((ext_vector_type(8))) short bf16x8;
typedef __attribute__((ext_vector_type(4))) float f32x4;
typedef __attribute__((ext_vector_type(2))) float f32x2;

__device__ __forceinline__ ushort bf16rn(float f) {
    uint u = __float_as_uint(f);
    u += 0x7fffu + ((u >> 16) & 1u);
    return (ushort)(u >> 16);
}
__device__ __forceinline__ float bflo(uint u) { return __uint_as_float(u << 16); }
__device__ __forceinline__ float bfhi(uint u) { return __uint_as_float(u & 0xffff0000u); }

// ---------------------------------------------------------------------------
// CSR build via two-level bucket sort -> PADDED per-node edge lists.
// Padding entries point at row N_NODES (all-zero row in tl).
// ---------------------------------------------------------------------------

__global__ __launch_bounds__(256) void hist_kernel(const int* __restrict__ dst,
                                                   int* __restrict__ ghist) {
    __shared__ int hist[NBUCK];
    int b = blockIdx.x, t = threadIdx.x;
    for (int i = t; i < NBUCK; i += 256) hist[i] = 0;
    __syncthreads();
    int e0 = b * EPB;
    for (int i = 0; i < EPB; i += 256) {
        int e = e0 + i + t;
        if (e < N_EDGES) atomicAdd(&hist[dst[e] >> BSH], 1);
    }
    __syncthreads();
    for (int i = t; i < NBUCK; i += 256) ghist[i * NBUCK + b] = hist[i];
}

__global__ __launch_bounds__(256) void scan1_kernel(const int* __restrict__ ghist,
                                                    int* __restrict__ bsum) {
    __shared__ int wsum[4];
    int b = blockIdx.x, t = threadIdx.x;
    int i4 = b * 256 + t;
    int4 v = (i4 * 4 < NHB) ? ((const int4*)ghist)[i4] : make_int4(0, 0, 0, 0);
    int s = v.x + v.y + v.z + v.w;
#pragma unroll
    for (int off = 32; off; off >>= 1) s += __shfl_down(s, off);
    if ((t & 63) == 0) wsum[t >> 6] = s;
    __syncthreads();
    if (t == 0) bsum[b] = wsum[0] + wsum[1] + wsum[2] + wsum[3];
}

__global__ void scan2_kernel(const int* __restrict__ bsum, int* __restrict__ boff,
                             int* __restrict__ gbb) {
    int lane = threadIdx.x;
    int v = (lane < NSB) ? bsum[lane] : 0;
    int s = v;
#pragma unroll
    for (int off = 1; off <= 32; off <<= 1) {
        int t2 = __shfl_up(s, off);
        if (lane >= off) s += t2;
    }
    if (lane < NSB) boff[lane] = s - v;
    if (lane == 0) gbb[NBUCK] = N_EDGES;
}

__global__ __launch_bounds__(256) void scan3_kernel(int* __restrict__ ghist,
                                                    const int* __restrict__ boff,
                                                    int* __restrict__ gbb) {
    __shared__ int ts[256];
    int b = blockIdx.x, t = threadIdx.x;
    int i4 = b * 256 + t;
    bool ok = (i4 * 4) < NHB;
    int4 v = ok ? ((const int4*)ghist)[i4] : make_int4(0, 0, 0, 0);
    int s = v.x + v.y + v.z + v.w;
    ts[t] = s;
    __syncthreads();
    for (int off = 1; off < 256; off <<= 1) {
        int a = (t >= off) ? ts[t - off] : 0;
        __syncthreads();
        ts[t] += a;
        __syncthreads();
    }
    int excl = boff[b] + ((t > 0) ? ts[t - 1] : 0);
    if (ok) {
        int idx = i4 * 4;
        int4 w;
        w.x = excl;
        w.y = excl + v.x;
        w.z = excl + v.x + v.y;
        w.w = excl + v.x + v.y + v.z;
        ((int4*)ghist)[i4] = w;
        if (idx % NBUCK == 0) gbb[idx / NBUCK] = w.x;
    }
}

__global__ __launch_bounds__(256) void scatter_kernel(const int* __restrict__ src,
                                                      const int* __restrict__ dst,
                                                      const int* __restrict__ ghist,
                                                      uint* __restrict__ scat) {
    __shared__ int base[NBUCK];
    __shared__ int fill[NBUCK];
    int b = blockIdx.x, t = threadIdx.x;
    for (int i = t; i < NBUCK; i += 256) { base[i] = ghist[i * NBUCK + b]; fill[i] = 0; }
    __syncthreads();
    int e0 = b * EPB;
    for (int i = 0; i < EPB; i += 256) {
        int e = e0 + i + t;
        if (e < N_EDGES) {
            int d = dst[e];
            int sv = src[e];
            int bk = d >> BSH;
            int lp = atomicAdd(&fill[bk], 1);
            scat[base[bk] + lp] = (uint)sv | ((uint)(d & 511) << 17);
        }
    }
}

__global__ __launch_bounds__(256) void bucket_csr_kernel(const uint* __restrict__ scat,
                                                         const int* __restrict__ gbb,
                                                         int* __restrict__ prow,
                                                         int* __restrict__ deg,
                                                         int* __restrict__ peidx) {
    __shared__ int cnt[512], fl[512], pref[512];
    __shared__ int ts[256];
    __shared__ int tot_s;
    int b = blockIdx.x, t = threadIdx.x;
    int beg = gbb[b], end = gbb[b + 1];
    int pb = beg + b * 8192;
    cnt[t] = 0; cnt[t + 256] = 0;
    __syncthreads();
    for (int i = beg + t; i < end; i += 256)
        atomicAdd(&cnt[scat[i] >> 17], 1);
    __syncthreads();
    int c0 = cnt[2 * t], c1 = cnt[2 * t + 1];
    int p0 = (c0 + 15) & ~15, p1 = (c1 + 15) & ~15;
    ts[t] = p0 + p1;
    __syncthreads();
    for (int off = 1; off < 256; off <<= 1) {
        int v = (t >= off) ? ts[t - off] : 0;
        __syncthreads();
        ts[t] += v;
        __syncthreads();
    }
    int ex = (t > 0) ? ts[t - 1] : 0;
    pref[2 * t] = ex;
    pref[2 * t + 1] = ex + p0;
    fl[t] = 0; fl[t + 256] = 0;
    if (t == 255) tot_s = ts[255];
    int g0 = b * 512 + 2 * t;
    if (g0 < N_NODES) { prow[g0] = pb + ex; deg[g0] = c0; }
    if (g0 + 1 < N_NODES) { prow[g0 + 1] = pb + ex + p0; deg[g0 + 1] = c1; }
    __syncthreads();
    int tot = tot_s;
    for (int i = t; i < tot; i += 256) peidx[pb + i] = N_NODES;  // pad -> zero row
    __syncthreads();
    for (int i = beg + t; i < end; i += 256) {
        uint w = scat[i];
        int nl = (int)(w >> 17);
        int lp = atomicAdd(&fl[nl], 1);
        peidx[pb + pref[nl] + lp] = (int)(w & 0x1FFFFu);
    }
}

// ---------------------------------------------------------------------------
// Prep: B packed in MFMA FRAGMENT order:
//   Bf[((kb*16 + tt)*64 + lane)*8 + e] = B[tt*16 + (lane&15)][kb*32 + (lane>>4)*8 + e]
// where B[n][k] = n<128 ? wl[k][n] : wr[k][n-128]. One fragment load in the
// GEMM K-loop is then a fully-coalesced 1KB global_load_dwordx4.
// ---------------------------------------------------------------------------
__global__ void prep_weights_kernel(const float* __restrict__ wl, const float* __restrict__ wr,
                                    ushort* __restrict__ Bf, int K) {
    int kb = blockIdx.x >> 4;       // K-step (32 wide)
    int tt = blockIdx.x & 15;       // col tile
    int lane = threadIdx.x;
    int n = tt * 16 + (lane & 15);
    int k0 = kb * 32 + (lane >> 4) * 8;
    ushort* dst = Bf + ((size_t)(kb * 16 + tt) * 64 + lane) * 8;
#pragma unroll
    for (int e = 0; e < 8; ++e) {
        int k = k0 + e;
        float v = (n < HID) ? wl[k * HID + n] : wr[k * HID + (n - HID)];
        dst[e] = bf16rn(v);
    }
}

__global__ void bn_prep_kernel(const float* __restrict__ bl0, const float* __restrict__ g0,
                               const float* __restrict__ be0, const float* __restrict__ rm0,
                               const float* __restrict__ rv0,
                               const float* __restrict__ bl1, const float* __restrict__ g1,
                               const float* __restrict__ be1, const float* __restrict__ rm1,
                               const float* __restrict__ rv1,
                               const float* __restrict__ bl2, const float* __restrict__ g2,
                               const float* __restrict__ be2, const float* __restrict__ rm2,
                               const float* __restrict__ rv2,
                               float* __restrict__ scale, float* __restrict__ shift) {
    int t = threadIdx.x;
    int L = t >> 7, j = t & 127;
    const float* bl = (L == 0) ? bl0 : (L == 1) ? bl1 : bl2;
    const float* g  = (L == 0) ? g0  : (L == 1) ? g1  : g2;
    const float* be = (L == 0) ? be0 : (L == 1) ? be1 : be2;
    const float* rm = (L == 0) ? rm0 : (L == 1) ? rm1 : rm2;
    const float* rv = (L == 0) ? rv0 : (L == 1) ? rv1 : rv2;
    float s = g[j] * rsqrtf(rv[j] + BN_EPS);
    scale[t] = s;
    shift[t] = (bl[j] - rm[j]) * s + be[j];
}

// ---------------------------------------------------------------------------
// GEMM (merged N, fragment-packed B): [tl | troot] = A @ [wl | wr].
// Block = 128 rows x 256 cols, grid 782. A staged once in LDS (XOR swizzle).
// Wave = 32 rows x 256 cols: per K-step 2 ds_read A-frags + 16 coalesced
// 1KB B-frag loads + 32 MFMAs (B reused for both row tiles immediately).
// Epilogue: per-wave LDS repack -> coalesced 256B row stores, 2x2 passes.
// ---------------------------------------------------------------------------
template <int K, bool AFP32>
__global__ __launch_bounds__(256) void gemm_kernel(const void* __restrict__ A_,
                                                   const ushort* __restrict__ Bf,
                                                   ushort* __restrict__ tl,
                                                   ushort* __restrict__ troot) {
    constexpr int CPR = K / 8;                 // 16B chunks per row
    constexpr int FULLG = CPR & ~7;            // start of partial swizzle group
    __shared__ ushort ldsA[128 * K];           // 32 KB (K=128) / 40 KB (K=160)
    const int t = threadIdx.x;
    const int m0b = blockIdx.x * 128;

    // ---- Stage A tile (128 rows x K) ----
#pragma unroll
    for (int i = 0; i < (128 * CPR) / 256; ++i) {
        int cidx = i * 256 + t;
        int row = cidx / CPR;
        int j = cidx - row * CPR;
        bf16x8 v;
        if (AFP32) {
            const float* A = (const float*)A_;
            int m = m0b + row;
            float4 f0 = make_float4(0.f, 0.f, 0.f, 0.f), f1 = f0;
            if (m < N_NODES) {
                f0 = *(const float4*)(A + (size_t)m * K + j * 8);
                f1 = *(const float4*)(A + (size_t)m * K + j * 8 + 4);
            }
            v[0] = (short)bf16rn(f0.x); v[1] = (short)bf16rn(f0.y);
            v[2] = (short)bf16rn(f0.z); v[3] = (short)bf16rn(f0.w);
            v[4] = (short)bf16rn(f1.x); v[5] = (short)bf16rn(f1.y);
            v[6] = (short)bf16rn(f1.z); v[7] = (short)bf16rn(f1.w);
        } else {
            const ushort* A = (const ushort*)A_;
            v = *(const bf16x8*)(A + (size_t)(m0b + row) * K + j * 8);
        }
        int swz = (j < FULLG) ? ((j & ~7) | ((j ^ row) & 7))
                              : ((j & ~3) | ((j ^ row) & 3));
        *(bf16x8*)&ldsA[row * K + swz * 8] = v;
    }
    __syncthreads();

    // ---- K-loop ----
    const int lane = threadIdx.x & 63;
    const int wv = threadIdx.x >> 6;
    const int col = lane & 15;
    const int q = lane >> 4;
    const int row0 = wv * 32 + col;            // row0 & 7 == col & 7
    f32x4 acc0[16], acc1[16];
#pragma unroll
    for (int tt = 0; tt < 16; ++tt) {
        acc0[tt] = (f32x4){0.f, 0.f, 0.f, 0.f};
        acc1[tt] = (f32x4){0.f, 0.f, 0.f, 0.f};
    }

#pragma unroll
    for (int kb = 0; kb < K / 32; ++kb) {
        int jj = kb * 4 + q;
        int swzj = (jj < FULLG) ? ((jj & ~7) | ((jj ^ col) & 7))
                                : ((jj & ~3) | ((jj ^ col) & 3));
        bf16x8 a0 = *(const bf16x8*)&ldsA[row0 * K + swzj * 8];
        bf16x8 a1 = *(const bf16x8*)&ldsA[(row0 + 16) * K + swzj * 8];
        const ushort* bp = Bf + ((size_t)kb * 16 * 64 + lane) * 8;
#pragma unroll
        for (int tt = 0; tt < 16; ++tt) {
            bf16x8 bfr = *(const bf16x8*)(bp + (size_t)tt * 64 * 8);
            acc0[tt] = __builtin_amdgcn_mfma_f32_16x16x32_bf16(a0, bfr, acc0[tt], 0, 0, 0);
            acc1[tt] = __builtin_amdgcn_mfma_f32_16x16x32_bf16(a1, bfr, acc1[tt], 0, 0, 0);
        }
    }

    // ---- Epilogue: per-wave LDS repack, coalesced stores ----
    __syncthreads();   // all waves done reading A region before aliasing
    ushort(*rp)[16][LPAD] = (ushort(*)[16][LPAD])ldsA;
#pragma unroll
    for (int mt = 0; mt < 2; ++mt) {
        const f32x4* ac = mt ? acc1 : acc0;
        int mbase = m0b + wv * 32 + mt * 16;
#pragma unroll
        for (int pass = 0; pass < 2; ++pass) {
            ushort* outp = pass ? troot : tl;
#pragma unroll
            for (int tt = 0; tt < 8; ++tt)
#pragma unroll
                for (int r = 0; r < 4; ++r)
                    rp[wv][q * 4 + r][tt * 16 + col] = bf16rn(ac[pass * 8 + tt][r]);
#pragma unroll
            for (int i = 0; i < 4; ++i) {
                int lin = i * 64 + lane;
                int row = lin >> 4;      // 4 rows per instr (16 lanes x 16B)
                int c16 = lin & 15;
                bf16x8 v = *(const bf16x8*)&rp[wv][row][c16 * 8];
                *(bf16x8*)(outp + (size_t)(mbase + row) * HID + c16 * 8) = v;
            }
        }
    }
}

// ---------------------------------------------------------------------------
// Aggregation + BN + ReLU (+ fused final linear).
// Wave = 4 nodes (16 lanes each); per-lane addresses -> 4 edge rows (1024B)
// per vmem instruction. Padding gathers hit the zero row (N_NODES); h's pad
// rows zeroed for the next GEMM (grid covers M_PAD).
// ---------------------------------------------------------------------------
template <bool FINAL>
__global__ __launch_bounds__(256) void agg_kernel(
    const ushort* __restrict__ tl_, const ushort* __restrict__ troot_,
    const int* __restrict__ prow, const int* __restrict__ deg_,
    const int* __restrict__ peidx,
    const float* __restrict__ bnscale, const float* __restrict__ bnshift,
    const float* __restrict__ linw, const float* __restrict__ linb,
    ushort* __restrict__ hout, float* __restrict__ out) {
    const int lane = threadIdx.x & 63;
    const int wvg = (blockIdx.x * 256 + (int)threadIdx.x) >> 6;
    const int g = lane >> 4;          // group 0..3 -> node
    const int s = lane & 15;          // feat slice: feats s*8 .. s*8+7
    const int n = wvg * 4 + g;        // < M_PAD by grid construction
    const int nn = (n < N_NODES) ? n : (N_NODES - 1);

    float4 sc0 = *(const float4*)(bnscale + s * 8);
    float4 sc1 = *(const float4*)(bnscale + s * 8 + 4);
    float4 sh0 = *(const float4*)(bnshift + s * 8);
    float4 sh1 = *(const float4*)(bnshift + s * 8 + 4);

    int pbeg = prow[nn];
    int dg = (n < N_NODES) ? deg_[nn] : 0;
    int myb = (dg + 15) >> 4;         // batches of 16 edges

    f32x2 acc2[4];
#pragma unroll
    for (int i = 0; i < 4; ++i) acc2[i] = (f32x2){0.f, 0.f};

    const int gsel = (lane & 48) << 2;   // bpermute byte-addr base of my group

    for (int b = 0;; ++b) {
        bool act = b < myb;
        if (!__any(act)) break;
        int idx = act ? peidx[pbeg + b * 16 + s] : N_NODES;  // 16 ids (or zero row)
        uint4 u[16];
#pragma unroll
        for (int jj = 0; jj < 16; ++jj) {
            int src = __builtin_amdgcn_ds_bpermute(gsel | (jj << 2), idx);
            u[jj] = *(const uint4*)(tl_ + (size_t)src * HID + s * 8);
        }
#pragma unroll
        for (int jj = 0; jj < 16; ++jj) {
            acc2[0] += (f32x2){bflo(u[jj].x), bfhi(u[jj].x)};
            acc2[1] += (f32x2){bflo(u[jj].y), bfhi(u[jj].y)};
            acc2[2] += (f32x2){bflo(u[jj].z), bfhi(u[jj].z)};
            acc2[3] += (f32x2){bflo(u[jj].w), bfhi(u[jj].w)};
        }
    }

    float inv = 1.0f / (float)((dg > 0) ? dg : 1);
    uint4 rv = *(const uint4*)(troot_ + (size_t)nn * HID + s * 8);
    float o[8];
    o[0] = fmaxf(fmaf(fmaf(acc2[0].x, inv, bflo(rv.x)), sc0.x, sh0.x), 0.f);
    o[1] = fmaxf(fmaf(fmaf(acc2[0].y, inv, bfhi(rv.x)), sc0.y, sh0.y), 0.f);
    o[2] = fmaxf(fmaf(fmaf(acc2[1].x, inv, bflo(rv.y)), sc0.z, sh0.z), 0.f);
    o[3] = fmaxf(fmaf(fmaf(acc2[1].y, inv, bfhi(rv.y)), sc0.w, sh0.w), 0.f);
    o[4] = fmaxf(fmaf(fmaf(acc2[2].x, inv, bflo(rv.z)), sc1.x, sh1.x), 0.f);
    o[5] = fmaxf(fmaf(fmaf(acc2[2].y, inv, bfhi(rv.z)), sc1.y, sh1.y), 0.f);
    o[6] = fmaxf(fmaf(fmaf(acc2[3].x, inv, bflo(rv.w)), sc1.z, sh1.z), 0.f);
    o[7] = fmaxf(fmaf(fmaf(acc2[3].y, inv, bfhi(rv.w)), sc1.w, sh1.w), 0.f);

    if (FINAL) {
        float4 w0 = *(const float4*)(linw + s * 8);
        float4 w1 = *(const float4*)(linw + s * 8 + 4);
        float p = o[0] * w0.x + o[1] * w0.y + o[2] * w0.z + o[3] * w0.w +
                  o[4] * w1.x + o[5] * w1.y + o[6] * w1.z + o[7] * w1.w;
#pragma unroll
        for (int off = 1; off < 16; off <<= 1) p += __shfl_xor(p, off);
        if (s == 0 && n < N_NODES) out[n] = p + linb[0];
    } else {
        uint4 pk = make_uint4(0u, 0u, 0u, 0u);
        if (n < N_NODES) {
            pk.x = (uint)bf16rn(o[0]) | ((uint)bf16rn(o[1]) << 16);
            pk.y = (uint)bf16rn(o[2]) | ((uint)bf16rn(o[3]) << 16);
            pk.z = (uint)bf16rn(o[4]) | ((uint)bf16rn(o[5]) << 16);
            pk.w = (uint)bf16rn(o[6]) | ((uint)bf16rn(o[7]) << 16);
        }
        *(uint4*)(hout + (size_t)n * HID + s * 8) = pk;   // pad rows -> zeros
    }
}

// ---------------------------------------------------------------------------

extern "C" void kernel_launch(void* const* d_in, const int* in_sizes, int n_in,
                              void* d_out, int out_size, void* d_ws, size_t ws_size,
                              hipStream_t stream) {
    const float* x    = (const float*)d_in[0];
    const int*   ei   = (const int*)d_in[1];
    const int*   esrc = ei;
    const int*   edst = ei + N_EDGES;
    const float* wl[3]; const float* wr[3]; const float* bl[3];
    const float* g[3];  const float* be[3]; const float* rm[3]; const float* rv[3];
    for (int i = 0; i < 3; ++i) {
        wl[i] = (const float*)d_in[2 + 7 * i];
        wr[i] = (const float*)d_in[3 + 7 * i];
        bl[i] = (const float*)d_in[4 + 7 * i];
        g[i]  = (const float*)d_in[5 + 7 * i];
        be[i] = (const float*)d_in[6 + 7 * i];
        rm[i] = (const float*)d_in[7 + 7 * i];
        rv[i] = (const float*)d_in[8 + 7 * i];
    }
    const float* lin_w = (const float*)d_in[23];
    const float* lin_b = (const float*)d_in[24];
    float* out = (float*)d_out;

    // Workspace carve-up (~98 MB total).
    char* ws = (char*)d_ws;
    size_t off = 0;
    auto carve = [&](size_t bytes) -> void* {
        void* p = ws + off;
        off += (bytes + 255) & ~(size_t)255;
        return p;
    };
    int*    prow   = (int*)carve((size_t)(N_NODES + 8) * sizeof(int));
    int*    deg    = (int*)carve((size_t)(N_NODES + 8) * sizeof(int));
    int*    peidx  = (int*)carve((size_t)3210000 * sizeof(int));   // padded CSR
    uint*   scat   = (uint*)carve((size_t)N_EDGES * sizeof(uint));
    int*    ghist  = (int*)carve((size_t)(NSB * 1024) * sizeof(int));
    int*    gbb    = (int*)carve((NBUCK + 4) * sizeof(int));
    int*    bsum   = (int*)carve((NSB + 2) * sizeof(int));
    int*    boff   = (int*)carve((NSB + 2) * sizeof(int));
    ushort* tl     = (ushort*)carve((size_t)(M_PAD + 1) * HID * sizeof(ushort));
    ushort* troot  = (ushort*)carve((size_t)M_PAD * HID * sizeof(ushort));
    ushort* h      = (ushort*)carve((size_t)M_PAD * HID * sizeof(ushort));
    ushort* Bf0    = (ushort*)carve(256 * IN_DIM * sizeof(ushort));
    ushort* Bf1    = (ushort*)carve(256 * HID * sizeof(ushort));
    ushort* Bf2    = (ushort*)carve(256 * HID * sizeof(ushort));
    float*  bnsc   = (float*)carve(3 * HID * sizeof(float));
    float*  bnsh   = (float*)carve(3 * HID * sizeof(float));
    (void)ws_size; (void)n_in; (void)in_sizes; (void)out_size;

    hist_kernel<<<NBUCK, 256, 0, stream>>>(edst, ghist);
    scan1_kernel<<<NSB, 256, 0, stream>>>(ghist, bsum);
    scan2_kernel<<<1, 64, 0, stream>>>(bsum, boff, gbb);
    scan3_kernel<<<NSB, 256, 0, stream>>>(ghist, boff, gbb);
    scatter_kernel<<<NBUCK, 256, 0, stream>>>(esrc, edst, ghist, scat);
    bucket_csr_kernel<<<NBUCK, 256, 0, stream>>>(scat, gbb, prow, deg, peidx);

    prep_weights_kernel<<<(IN_DIM / 32) * 16, 64, 0, stream>>>(wl[0], wr[0], Bf0, IN_DIM);
    prep_weights_kernel<<<(HID / 32) * 16, 64, 0, stream>>>(wl[1], wr[1], Bf1, HID);
    prep_weights_kernel<<<(HID / 32) * 16, 64, 0, stream>>>(wl[2], wr[2], Bf2, HID);
    bn_prep_kernel<<<1, 384, 0, stream>>>(bl[0], g[0], be[0], rm[0], rv[0],
                                          bl[1], g[1], be[1], rm[1], rv[1],
                                          bl[2], g[2], be[2], rm[2], rv[2],
                                          bnsc, bnsh);

    const int GEMM_GRID = M_PAD / 128;          // 782 blocks, 128 rows x 256 cols
    const int AGG_GRID = M_PAD / 16;            // 6256: covers pad rows too

    gemm_kernel<IN_DIM, true><<<GEMM_GRID, 256, 0, stream>>>(x, Bf0, tl, troot);
    agg_kernel<false><<<AGG_GRID, 256, 0, stream>>>(tl, troot, prow, deg, peidx, bnsc, bnsh,
                                                    nullptr, nullptr, h, nullptr);
    gemm_kernel<HID, false><<<GEMM_GRID, 256, 0, stream>>>(h, Bf1, tl, troot);
    agg_kernel<false><<<AGG_GRID, 256, 0, stream>>>(tl, troot, prow, deg, peidx, bnsc + HID, bnsh + HID,
                                                    nullptr, nullptr, h, nullptr);
    gemm_kernel<HID, false><<<GEMM_GRID, 256, 0, stream>>>(h, Bf2, tl, troot);
    agg_kernel<true><<<AGG_GRID, 256, 0, stream>>>(tl, troot, prow, deg, peidx, bnsc + 2 * HID, bnsh + 2 * HID,
                                                   lin_w, lin_b, nullptr, out);
}

// Round 10
// 464.838 us; speedup vs baseline: 1.2509x; 1.1537x over previous
//
#include <hip/hip_runtime.h>

#define N_NODES 100000
#define N_EDGES 1600000
#define IN_DIM 160
#define HID 128
#define BN_EPS 1e-5f

#define M_PAD 100096   // 1564 * 64 rows (GEMM block = 64 rows)
#define NBUCK 196      // 512-node buckets (196*512 = 100352 >= N_NODES)
#define BSH 9
#define EPB 8192       // edges per block in hist/scatter kernels
#define NHB (NBUCK * NBUCK)   // 38416, divisible by 4
#define NSB 38         // scan blocks: 38*1024 = 38912 >= NHB
#define LPAD 132       // gemm LDS repack row stride (ushorts)

typedef unsigned int uint;
typedef unsigned short ushort;
typedef __attribute__((ext_vector_type(8))) short bf16x8;
typedef __attribute__((ext_vector_type(4))) float f32x4;
typedef __attribute__((ext_vector_type(2))) float f32x2;

__device__ __forceinline__ ushort bf16rn(float f) {
    uint u = __float_as_uint(f);
    u += 0x7fffu + ((u >> 16) & 1u);
    return (ushort)(u >> 16);
}
__device__ __forceinline__ float bflo(uint u) { return __uint_as_float(u << 16); }
__device__ __forceinline__ float bfhi(uint u) { return __uint_as_float(u & 0xffff0000u); }

// ---------------------------------------------------------------------------
// CSR build via two-level bucket sort -> PADDED per-node edge lists.
// Padding entries point at row N_NODES (all-zero row in tl).
// ---------------------------------------------------------------------------

__global__ __launch_bounds__(256) void hist_kernel(const int* __restrict__ dst,
                                                   int* __restrict__ ghist) {
    __shared__ int hist[NBUCK];
    int b = blockIdx.x, t = threadIdx.x;
    for (int i = t; i < NBUCK; i += 256) hist[i] = 0;
    __syncthreads();
    int e0 = b * EPB;
    for (int i = 0; i < EPB; i += 256) {
        int e = e0 + i + t;
        if (e < N_EDGES) atomicAdd(&hist[dst[e] >> BSH], 1);
    }
    __syncthreads();
    for (int i = t; i < NBUCK; i += 256) ghist[i * NBUCK + b] = hist[i];
}

__global__ __launch_bounds__(256) void scan1_kernel(const int* __restrict__ ghist,
                                                    int* __restrict__ bsum) {
    __shared__ int wsum[4];
    int b = blockIdx.x, t = threadIdx.x;
    int i4 = b * 256 + t;
    int4 v = (i4 * 4 < NHB) ? ((const int4*)ghist)[i4] : make_int4(0, 0, 0, 0);
    int s = v.x + v.y + v.z + v.w;
#pragma unroll
    for (int off = 32; off; off >>= 1) s += __shfl_down(s, off);
    if ((t & 63) == 0) wsum[t >> 6] = s;
    __syncthreads();
    if (t == 0) bsum[b] = wsum[0] + wsum[1] + wsum[2] + wsum[3];
}

__global__ void scan2_kernel(const int* __restrict__ bsum, int* __restrict__ boff,
                             int* __restrict__ gbb) {
    int lane = threadIdx.x;
    int v = (lane < NSB) ? bsum[lane] : 0;
    int s = v;
#pragma unroll
    for (int off = 1; off <= 32; off <<= 1) {
        int t2 = __shfl_up(s, off);
        if (lane >= off) s += t2;
    }
    if (lane < NSB) boff[lane] = s - v;
    if (lane == 0) gbb[NBUCK] = N_EDGES;
}

__global__ __launch_bounds__(256) void scan3_kernel(int* __restrict__ ghist,
                                                    const int* __restrict__ boff,
                                                    int* __restrict__ gbb) {
    __shared__ int ts[256];
    int b = blockIdx.x, t = threadIdx.x;
    int i4 = b * 256 + t;
    bool ok = (i4 * 4) < NHB;
    int4 v = ok ? ((const int4*)ghist)[i4] : make_int4(0, 0, 0, 0);
    int s = v.x + v.y + v.z + v.w;
    ts[t] = s;
    __syncthreads();
    for (int off = 1; off < 256; off <<= 1) {
        int a = (t >= off) ? ts[t - off] : 0;
        __syncthreads();
        ts[t] += a;
        __syncthreads();
    }
    int excl = boff[b] + ((t > 0) ? ts[t - 1] : 0);
    if (ok) {
        int idx = i4 * 4;
        int4 w;
        w.x = excl;
        w.y = excl + v.x;
        w.z = excl + v.x + v.y;
        w.w = excl + v.x + v.y + v.z;
        ((int4*)ghist)[i4] = w;
        if (idx % NBUCK == 0) gbb[idx / NBUCK] = w.x;
    }
}

__global__ __launch_bounds__(256) void scatter_kernel(const int* __restrict__ src,
                                                      const int* __restrict__ dst,
                                                      const int* __restrict__ ghist,
                                                      uint* __restrict__ scat) {
    __shared__ int base[NBUCK];
    __shared__ int fill[NBUCK];
    int b = blockIdx.x, t = threadIdx.x;
    for (int i = t; i < NBUCK; i += 256) { base[i] = ghist[i * NBUCK + b]; fill[i] = 0; }
    __syncthreads();
    int e0 = b * EPB;
    for (int i = 0; i < EPB; i += 256) {
        int e = e0 + i + t;
        if (e < N_EDGES) {
            int d = dst[e];
            int sv = src[e];
            int bk = d >> BSH;
            int lp = atomicAdd(&fill[bk], 1);
            scat[base[bk] + lp] = (uint)sv | ((uint)(d & 511) << 17);
        }
    }
}

__global__ __launch_bounds__(256) void bucket_csr_kernel(const uint* __restrict__ scat,
                                                         const int* __restrict__ gbb,
                                                         int* __restrict__ prow,
                                                         int* __restrict__ deg,
                                                         int* __restrict__ peidx) {
    __shared__ int cnt[512], fl[512], pref[512];
    __shared__ int ts[256];
    __shared__ int tot_s;
    int b = blockIdx.x, t = threadIdx.x;
    int beg = gbb[b], end = gbb[b + 1];
    int pb = beg + b * 8192;
    cnt[t] = 0; cnt[t + 256] = 0;
    __syncthreads();
    for (int i = beg + t; i < end; i += 256)
        atomicAdd(&cnt[scat[i] >> 17], 1);
    __syncthreads();
    int c0 = cnt[2 * t], c1 = cnt[2 * t + 1];
    int p0 = (c0 + 15) & ~15, p1 = (c1 + 15) & ~15;
    ts[t] = p0 + p1;
    __syncthreads();
    for (int off = 1; off < 256; off <<= 1) {
        int v = (t >= off) ? ts[t - off] : 0;
        __syncthreads();
        ts[t] += v;
        __syncthreads();
    }
    int ex = (t > 0) ? ts[t - 1] : 0;
    pref[2 * t] = ex;
    pref[2 * t + 1] = ex + p0;
    fl[t] = 0; fl[t + 256] = 0;
    if (t == 255) tot_s = ts[255];
    int g0 = b * 512 + 2 * t;
    if (g0 < N_NODES) { prow[g0] = pb + ex; deg[g0] = c0; }
    if (g0 + 1 < N_NODES) { prow[g0 + 1] = pb + ex + p0; deg[g0 + 1] = c1; }
    __syncthreads();
    int tot = tot_s;
    for (int i = t; i < tot; i += 256) peidx[pb + i] = N_NODES;  // pad -> zero row
    __syncthreads();
    for (int i = beg + t; i < end; i += 256) {
        uint w = scat[i];
        int nl = (int)(w >> 17);
        int lp = atomicAdd(&fl[nl], 1);
        peidx[pb + pref[nl] + lp] = (int)(w & 0x1FFFFu);
    }
}

// ---------------------------------------------------------------------------
// Prep: B packed in MFMA FRAGMENT order:
//   Bf[((kb*16 + tt)*64 + lane)*8 + e] = B[tt*16 + (lane&15)][kb*32 + (lane>>4)*8 + e]
// ---------------------------------------------------------------------------
__global__ void prep_weights_kernel(const float* __restrict__ wl, const float* __restrict__ wr,
                                    ushort* __restrict__ Bf, int K) {
    int kb = blockIdx.x >> 4;       // K-step (32 wide)
    int tt = blockIdx.x & 15;       // col tile
    int lane = threadIdx.x;
    int n = tt * 16 + (lane & 15);
    int k0 = kb * 32 + (lane >> 4) * 8;
    ushort* dst = Bf + ((size_t)(kb * 16 + tt) * 64 + lane) * 8;
#pragma unroll
    for (int e = 0; e < 8; ++e) {
        int k = k0 + e;
        float v = (n < HID) ? wl[k * HID + n] : wr[k * HID + (n - HID)];
        dst[e] = bf16rn(v);
    }
}

__global__ void bn_prep_kernel(const float* __restrict__ bl0, const float* __restrict__ g0,
                               const float* __restrict__ be0, const float* __restrict__ rm0,
                               const float* __restrict__ rv0,
                               const float* __restrict__ bl1, const float* __restrict__ g1,
                               const float* __restrict__ be1, const float* __restrict__ rm1,
                               const float* __restrict__ rv1,
                               const float* __restrict__ bl2, const float* __restrict__ g2,
                               const float* __restrict__ be2, const float* __restrict__ rm2,
                               const float* __restrict__ rv2,
                               float* __restrict__ scale, float* __restrict__ shift) {
    int t = threadIdx.x;
    int L = t >> 7, j = t & 127;
    const float* bl = (L == 0) ? bl0 : (L == 1) ? bl1 : bl2;
    const float* g  = (L == 0) ? g0  : (L == 1) ? g1  : g2;
    const float* be = (L == 0) ? be0 : (L == 1) ? be1 : be2;
    const float* rm = (L == 0) ? rm0 : (L == 1) ? rm1 : rm2;
    const float* rv = (L == 0) ? rv0 : (L == 1) ? rv1 : rv2;
    float s = g[j] * rsqrtf(rv[j] + BN_EPS);
    scale[t] = s;
    shift[t] = (bl[j] - rm[j]) * s + be[j];
}

// ---------------------------------------------------------------------------
// GEMM: [tl | troot] = A @ [wl | wr]. Block = 64 rows x 256 cols, grid 1564.
// A staged once in LDS (XOR swizzle). Wave = 32 rows x 128 cols:
//   rh = wv&1  -> rows rh*32 .. rh*32+31 (two 16-row MFMA tiles)
//   ch = wv>>1 -> cols ch*128 (8 col tiles); wave writes tl (ch=0) or troot.
// Per K-step: 2 ds_read A-frags + 8 coalesced 1KB B-frag loads + 16 MFMAs.
// acc = 64 VGPRs/wave -> ~5 blocks/CU resident (latency hidden by TLP).
// ---------------------------------------------------------------------------
template <int K, bool AFP32>
__global__ __launch_bounds__(256) void gemm_kernel(const void* __restrict__ A_,
                                                   const ushort* __restrict__ Bf,
                                                   ushort* __restrict__ tl,
                                                   ushort* __restrict__ troot) {
    constexpr int CPR = K / 8;                 // 16B chunks per row
    constexpr int FULLG = CPR & ~7;            // start of partial swizzle group
    constexpr int LDSE = (64 * K > 4 * 16 * LPAD) ? 64 * K : 4 * 16 * LPAD;
    __shared__ ushort ldsA[LDSE];              // 20.5 KB (K=160) / 16.9 KB (K=128)
    const int t = threadIdx.x;
    const int m0b = blockIdx.x * 64;

    // ---- Stage A tile (64 rows x K) ----
#pragma unroll
    for (int i = 0; i < (64 * CPR) / 256; ++i) {
        int cidx = i * 256 + t;
        int row = cidx / CPR;
        int j = cidx - row * CPR;
        bf16x8 v;
        if (AFP32) {
            const float* A = (const float*)A_;
            int m = m0b + row;
            float4 f0 = make_float4(0.f, 0.f, 0.f, 0.f), f1 = f0;
            if (m < N_NODES) {
                f0 = *(const float4*)(A + (size_t)m * K + j * 8);
                f1 = *(const float4*)(A + (size_t)m * K + j * 8 + 4);
            }
            v[0] = (short)bf16rn(f0.x); v[1] = (short)bf16rn(f0.y);
            v[2] = (short)bf16rn(f0.z); v[3] = (short)bf16rn(f0.w);
            v[4] = (short)bf16rn(f1.x); v[5] = (short)bf16rn(f1.y);
            v[6] = (short)bf16rn(f1.z); v[7] = (short)bf16rn(f1.w);
        } else {
            const ushort* A = (const ushort*)A_;
            v = *(const bf16x8*)(A + (size_t)(m0b + row) * K + j * 8);
        }
        int swz = (j < FULLG) ? ((j & ~7) | ((j ^ row) & 7))
                              : ((j & ~3) | ((j ^ row) & 3));
        *(bf16x8*)&ldsA[row * K + swz * 8] = v;
    }
    __syncthreads();

    // ---- K-loop ----
    const int lane = threadIdx.x & 63;
    const int wv = threadIdx.x >> 6;
    const int col = lane & 15;
    const int q = lane >> 4;
    const int rh = wv & 1;
    const int ch = wv >> 1;
    const int row0 = rh * 32 + col;            // row0 & 7 == col & 7
    f32x4 acc0[8], acc1[8];
#pragma unroll
    for (int tt = 0; tt < 8; ++tt) {
        acc0[tt] = (f32x4){0.f, 0.f, 0.f, 0.f};
        acc1[tt] = (f32x4){0.f, 0.f, 0.f, 0.f};
    }

#pragma unroll
    for (int kb = 0; kb < K / 32; ++kb) {
        int jj = kb * 4 + q;
        int swzj = (jj < FULLG) ? ((jj & ~7) | ((jj ^ col) & 7))
                                : ((jj & ~3) | ((jj ^ col) & 3));
        bf16x8 a0 = *(const bf16x8*)&ldsA[row0 * K + swzj * 8];
        bf16x8 a1 = *(const bf16x8*)&ldsA[(row0 + 16) * K + swzj * 8];
        const ushort* bp = Bf + ((size_t)((kb * 16 + ch * 8) * 64) + lane) * 8;
#pragma unroll
        for (int tt = 0; tt < 8; ++tt) {
            bf16x8 bfr = *(const bf16x8*)(bp + (size_t)tt * 64 * 8);
            acc0[tt] = __builtin_amdgcn_mfma_f32_16x16x32_bf16(a0, bfr, acc0[tt], 0, 0, 0);
            acc1[tt] = __builtin_amdgcn_mfma_f32_16x16x32_bf16(a1, bfr, acc1[tt], 0, 0, 0);
        }
    }

    // ---- Epilogue: per-wave LDS repack (128 cols), coalesced 256B stores ----
    __syncthreads();   // all waves done reading A region before aliasing
    ushort(*rp)[16][LPAD] = (ushort(*)[16][LPAD])ldsA;
    ushort* outp = ch ? troot : tl;
#pragma unroll
    for (int mt = 0; mt < 2; ++mt) {
        const f32x4* ac = mt ? acc1 : acc0;
#pragma unroll
        for (int tt = 0; tt < 8; ++tt)
#pragma unroll
            for (int r = 0; r < 4; ++r)
                rp[wv][q * 4 + r][tt * 16 + col] = bf16rn(ac[tt][r]);
        int mbase = m0b + rh * 32 + mt * 16;
#pragma unroll
        for (int i = 0; i < 4; ++i) {
            int lin = i * 64 + lane;
            int row = lin >> 4;      // 4 rows per instr (16 lanes x 16B)
            int c16 = lin & 15;
            bf16x8 v = *(const bf16x8*)&rp[wv][row][c16 * 8];
            *(bf16x8*)(outp + (size_t)(mbase + row) * HID + c16 * 8) = v;
        }
    }
}

// ---------------------------------------------------------------------------
// Aggregation + BN + ReLU (+ fused final linear).
// Wave = 4 nodes (16 lanes each); per-lane addresses -> 4 edge rows (1024B)
// per vmem instruction. Padding gathers hit the zero row (N_NODES); h's pad
// rows zeroed for the next GEMM (grid covers M_PAD).
// ---------------------------------------------------------------------------
template <bool FINAL>
__global__ __launch_bounds__(256) void agg_kernel(
    const ushort* __restrict__ tl_, const ushort* __restrict__ troot_,
    const int* __restrict__ prow, const int* __restrict__ deg_,
    const int* __restrict__ peidx,
    const float* __restrict__ bnscale, const float* __restrict__ bnshift,
    const float* __restrict__ linw, const float* __restrict__ linb,
    ushort* __restrict__ hout, float* __restrict__ out) {
    const int lane = threadIdx.x & 63;
    const int wvg = (blockIdx.x * 256 + (int)threadIdx.x) >> 6;
    const int g = lane >> 4;          // group 0..3 -> node
    const int s = lane & 15;          // feat slice: feats s*8 .. s*8+7
    const int n = wvg * 4 + g;        // < M_PAD by grid construction
    const int nn = (n < N_NODES) ? n : (N_NODES - 1);

    float4 sc0 = *(const float4*)(bnscale + s * 8);
    float4 sc1 = *(const float4*)(bnscale + s * 8 + 4);
    float4 sh0 = *(const float4*)(bnshift + s * 8);
    float4 sh1 = *(const float4*)(bnshift + s * 8 + 4);

    int pbeg = prow[nn];
    int dg = (n < N_NODES) ? deg_[nn] : 0;
    int myb = (dg + 15) >> 4;         // batches of 16 edges

    f32x2 acc2[4];
#pragma unroll
    for (int i = 0; i < 4; ++i) acc2[i] = (f32x2){0.f, 0.f};

    const int gsel = (lane & 48) << 2;   // bpermute byte-addr base of my group

    for (int b = 0;; ++b) {
        bool act = b < myb;
        if (!__any(act)) break;
        int idx = act ? peidx[pbeg + b * 16 + s] : N_NODES;  // 16 ids (or zero row)
        uint4 u[16];
#pragma unroll
        for (int jj = 0; jj < 16; ++jj) {
            int src = __builtin_amdgcn_ds_bpermute(gsel | (jj << 2), idx);
            u[jj] = *(const uint4*)(tl_ + (size_t)src * HID + s * 8);
        }
#pragma unroll
        for (int jj = 0; jj < 16; ++jj) {
            acc2[0] += (f32x2){bflo(u[jj].x), bfhi(u[jj].x)};
            acc2[1] += (f32x2){bflo(u[jj].y), bfhi(u[jj].y)};
            acc2[2] += (f32x2){bflo(u[jj].z), bfhi(u[jj].z)};
            acc2[3] += (f32x2){bflo(u[jj].w), bfhi(u[jj].w)};
        }
    }

    float inv = 1.0f / (float)((dg > 0) ? dg : 1);
    uint4 rv = *(const uint4*)(troot_ + (size_t)nn * HID + s * 8);
    float o[8];
    o[0] = fmaxf(fmaf(fmaf(acc2[0].x, inv, bflo(rv.x)), sc0.x, sh0.x), 0.f);
    o[1] = fmaxf(fmaf(fmaf(acc2[0].y, inv, bfhi(rv.x)), sc0.y, sh0.y), 0.f);
    o[2] = fmaxf(fmaf(fmaf(acc2[1].x, inv, bflo(rv.y)), sc0.z, sh0.z), 0.f);
    o[3] = fmaxf(fmaf(fmaf(acc2[1].y, inv, bfhi(rv.y)), sc0.w, sh0.w), 0.f);
    o[4] = fmaxf(fmaf(fmaf(acc2[2].x, inv, bflo(rv.z)), sc1.x, sh1.x), 0.f);
    o[5] = fmaxf(fmaf(fmaf(acc2[2].y, inv, bfhi(rv.z)), sc1.y, sh1.y), 0.f);
    o[6] = fmaxf(fmaf(fmaf(acc2[3].x, inv, bflo(rv.w)), sc1.z, sh1.z), 0.f);
    o[7] = fmaxf(fmaf(fmaf(acc2[3].y, inv, bfhi(rv.w)), sc1.w, sh1.w), 0.f);

    if (FINAL) {
        float4 w0 = *(const float4*)(linw + s * 8);
        float4 w1 = *(const float4*)(linw + s * 8 + 4);
        float p = o[0] * w0.x + o[1] * w0.y + o[2] * w0.z + o[3] * w0.w +
                  o[4] * w1.x + o[5] * w1.y + o[6] * w1.z + o[7] * w1.w;
#pragma unroll
        for (int off = 1; off < 16; off <<= 1) p += __shfl_xor(p, off);
        if (s == 0 && n < N_NODES) out[n] = p + linb[0];
    } else {
        uint4 pk = make_uint4(0u, 0u, 0u, 0u);
        if (n < N_NODES) {
            pk.x = (uint)bf16rn(o[0]) | ((uint)bf16rn(o[1]) << 16);
            pk.y = (uint)bf16rn(o[2]) | ((uint)bf16rn(o[3]) << 16);
            pk.z = (uint)bf16rn(o[4]) | ((uint)bf16rn(o[5]) << 16);
            pk.w = (uint)bf16rn(o[6]) | ((uint)bf16rn(o[7]) << 16);
        }
        *(uint4*)(hout + (size_t)n * HID + s * 8) = pk;   // pad rows -> zeros
    }
}

// ---------------------------------------------------------------------------

extern "C" void kernel_launch(void* const* d_in, const int* in_sizes, int n_in,
                              void* d_out, int out_size, void* d_ws, size_t ws_size,
                              hipStream_t stream) {
    const float* x    = (const float*)d_in[0];
    const int*   ei   = (const int*)d_in[1];
    const int*   esrc = ei;
    const int*   edst = ei + N_EDGES;
    const float* wl[3]; const float* wr[3]; const float* bl[3];
    const float* g[3];  const float* be[3]; const float* rm[3]; const float* rv[3];
    for (int i = 0; i < 3; ++i) {
        wl[i] = (const float*)d_in[2 + 7 * i];
        wr[i] = (const float*)d_in[3 + 7 * i];
        bl[i] = (const float*)d_in[4 + 7 * i];
        g[i]  = (const float*)d_in[5 + 7 * i];
        be[i] = (const float*)d_in[6 + 7 * i];
        rm[i] = (const float*)d_in[7 + 7 * i];
        rv[i] = (const float*)d_in[8 + 7 * i];
    }
    const float* lin_w = (const float*)d_in[23];
    const float* lin_b = (const float*)d_in[24];
    float* out = (float*)d_out;

    // Workspace carve-up (~98 MB total).
    char* ws = (char*)d_ws;
    size_t off = 0;
    auto carve = [&](size_t bytes) -> void* {
        void* p = ws + off;
        off += (bytes + 255) & ~(size_t)255;
        return p;
    };
    int*    prow   = (int*)carve((size_t)(N_NODES + 8) * sizeof(int));
    int*    deg    = (int*)carve((size_t)(N_NODES + 8) * sizeof(int));
    int*    peidx  = (int*)carve((size_t)3210000 * sizeof(int));   // padded CSR
    uint*   scat   = (uint*)carve((size_t)N_EDGES * sizeof(uint));
    int*    ghist  = (int*)carve((size_t)(NSB * 1024) * sizeof(int));
    int*    gbb    = (int*)carve((NBUCK + 4) * sizeof(int));
    int*    bsum   = (int*)carve((NSB + 2) * sizeof(int));
    int*    boff   = (int*)carve((NSB + 2) * sizeof(int));
    ushort* tl     = (ushort*)carve((size_t)(M_PAD + 1) * HID * sizeof(ushort));
    ushort* troot  = (ushort*)carve((size_t)M_PAD * HID * sizeof(ushort));
    ushort* h      = (ushort*)carve((size_t)M_PAD * HID * sizeof(ushort));
    ushort* Bf0    = (ushort*)carve(256 * IN_DIM * sizeof(ushort));
    ushort* Bf1    = (ushort*)carve(256 * HID * sizeof(ushort));
    ushort* Bf2    = (ushort*)carve(256 * HID * sizeof(ushort));
    float*  bnsc   = (float*)carve(3 * HID * sizeof(float));
    float*  bnsh   = (float*)carve(3 * HID * sizeof(float));
    (void)ws_size; (void)n_in; (void)in_sizes; (void)out_size;

    hist_kernel<<<NBUCK, 256, 0, stream>>>(edst, ghist);
    scan1_kernel<<<NSB, 256, 0, stream>>>(ghist, bsum);
    scan2_kernel<<<1, 64, 0, stream>>>(bsum, boff, gbb);
    scan3_kernel<<<NSB, 256, 0, stream>>>(ghist, boff, gbb);
    scatter_kernel<<<NBUCK, 256, 0, stream>>>(esrc, edst, ghist, scat);
    bucket_csr_kernel<<<NBUCK, 256, 0, stream>>>(scat, gbb, prow, deg, peidx);

    prep_weights_kernel<<<(IN_DIM / 32) * 16, 64, 0, stream>>>(wl[0], wr[0], Bf0, IN_DIM);
    prep_weights_kernel<<<(HID / 32) * 16, 64, 0, stream>>>(wl[1], wr[1], Bf1, HID);
    prep_weights_kernel<<<(HID / 32) * 16, 64, 0, stream>>>(wl[2], wr[2], Bf2, HID);
    bn_prep_kernel<<<1, 384, 0, stream>>>(bl[0], g[0], be[0], rm[0], rv[0],
                                          bl[1], g[1], be[1], rm[1], rv[1],
                                          bl[2], g[2], be[2], rm[2], rv[2],
                                          bnsc, bnsh);

    const int GEMM_GRID = M_PAD / 64;           // 1564 blocks, 64 rows x 256 cols
    const int AGG_GRID = M_PAD / 16;            // 6256: covers pad rows too

    gemm_kernel<IN_DIM, true><<<GEMM_GRID, 256, 0, stream>>>(x, Bf0, tl, troot);
    agg_kernel<false><<<AGG_GRID, 256, 0, stream>>>(tl, troot, prow, deg, peidx, bnsc, bnsh,
                                                    nullptr, nullptr, h, nullptr);
    gemm_kernel<HID, false><<<GEMM_GRID, 256, 0, stream>>>(h, Bf1, tl, troot);
    agg_kernel<false><<<AGG_GRID, 256, 0, stream>>>(tl, troot, prow, deg, peidx, bnsc + HID, bnsh + HID,
                                                    nullptr, nullptr, h, nullptr);
    gemm_kernel<HID, false><<<GEMM_GRID, 256, 0, stream>>>(h, Bf2, tl, troot);
    agg_kernel<true><<<AGG_GRID, 256, 0, stream>>>(tl, troot, prow, deg, peidx, bnsc + 2 * HID, bnsh + 2 * HID,
                                                   lin_w, lin_b, nullptr, out);
}